// Round 10
// baseline (98.061 us; speedup 1.0000x reference)
//
#include <hip/hip_runtime.h>
#include <stdint.h>

// Conv2d as implicit GEMM, bf16 MFMA.
// R10: m97 regime — 128x128 tile, BK=32, 256 threads, 32KB LDS,
// 3 blocks/CU co-resident, plain double-buffered loop (compiler-managed waits,
// cross-block overlap hides barrier drains). Grid 1568 (~98% utilization).
// GEMM: M=100352, N=256, K=1152 (k=(kh*3+kw)*128+ci). 36 K-tiles of 32.

#define CIN   128
#define HW_   56
#define CO_   256
#define KSZ   1152
#define IMGHW 3136
#define HP    58
#define XT_BYTES ((size_t)32 * HP * HP * CIN * 2)   // 27,557,888
#define WP_BYTES ((size_t)CO_ * KSZ * 2)            // 589,824
#define WS_NEED  (XT_BYTES + WP_BYTES)

typedef __attribute__((ext_vector_type(8))) __bf16 bf16x8;
typedef __attribute__((ext_vector_type(4))) float f32x4;
typedef __attribute__((ext_vector_type(8))) unsigned short ushort8;

__device__ __forceinline__ unsigned short f2bf(float f) {
    unsigned int u = __float_as_uint(f);
    u += 0x7fffu + ((u >> 16) & 1u);   // RNE
    return (unsigned short)(u >> 16);
}

__device__ __forceinline__ void gl2lds16(const void* g, void* l) {
    __builtin_amdgcn_global_load_lds(
        (const __attribute__((address_space(1))) void*)g,
        (__attribute__((address_space(3))) void*)l, 16, 0, 0);
}

// ---- weight pack: [co][ci][kh][kw] f32 -> [co][k] bf16, k=(kh*3+kw)*128+ci
__global__ void pack_weight(const float* __restrict__ w,
                            unsigned short* __restrict__ wp) {
    int idx = blockIdx.x * 256 + threadIdx.x;
    int co = idx / KSZ;
    int k  = idx - co * KSZ;
    int khkw = k >> 7;
    int ci = k & 127;
    wp[idx] = f2bf(w[(co * CIN + ci) * 9 + khkw]);
}

// ---- x transform: NCHW f32 -> padded NHWC bf16 [32][58][58][128]
// float4 coalesced reads, ushort2 LDS transpose, dwordx4 stores. (R9-verified)
__global__ __launch_bounds__(256)
void xform(const float* __restrict__ x, unsigned short* __restrict__ xt) {
    const int nb = blockIdx.x;
    const int n  = nb / HP;
    const int hp = nb - n * HP;
    unsigned short* orow = xt + ((size_t)n * HP + hp) * (HP * CIN);
    const int t = threadIdx.x;

    if (hp == 0 || hp == HP - 1) {
        for (int i = t; i < (HP * CIN) / 8; i += 256)
            ((ushort8*)orow)[i] = (ushort8){0, 0, 0, 0, 0, 0, 0, 0};
        return;
    }
    const int h = hp - 1;
    __shared__ ushort2 T[CIN][31];              // w-pairs 0..27 used, stride 31
    {
        const int ci = t >> 1, part = t & 1;
        const float* src = x + (((size_t)n * CIN + ci) * IMGHW + h * HW_ + part * 28);
        #pragma unroll
        for (int j = 0; j < 7; ++j) {
            float4 v = *(const float4*)(src + 4 * j);
            T[ci][part * 14 + 2 * j]     = (ushort2){f2bf(v.x), f2bf(v.y)};
            T[ci][part * 14 + 2 * j + 1] = (ushort2){f2bf(v.z), f2bf(v.w)};
        }
    }
    __syncthreads();
    const int wpg = t >> 4, cig = t & 15;       // wp-stride 16, 8 ci per thread
    const int ci0 = cig * 8;
    for (int wp_ = wpg; wp_ < HP; wp_ += 16) {
        ushort8 v = (ushort8){0, 0, 0, 0, 0, 0, 0, 0};
        const int w_ = wp_ - 1;
        if ((unsigned)w_ < (unsigned)HW_) {
            #pragma unroll
            for (int e = 0; e < 8; ++e) {
                ushort2 p = T[ci0 + e][w_ >> 1];
                v[e] = (w_ & 1) ? p.y : p.x;
            }
        }
        *(ushort8*)(orow + wp_ * CIN + ci0) = v;
    }
}

// ---- main conv: 128x128 tile, BK=32, 4 waves (2m x 2n), wave 64x64
// LDS buf (16KB): A [64 row2][128B] @0, B [64 row2][128B] @8K.
// Paired-row layout (R6-verified, 0 conflicts): line holds rows {2r2, 2r2+1},
// logical chunk lc = parity*4 + kc, phys chunk = lc ^ (r2 & 7).
__global__ __launch_bounds__(256, 3)
void conv97(const unsigned short* __restrict__ xt,
            const unsigned short* __restrict__ wpk,
            float* __restrict__ out)
{
    __shared__ __align__(16) char lds[2][16384];   // 32 KiB

    const int tid  = threadIdx.x;
    const int lane = tid & 63;
    const int wid  = tid >> 6;

    int bid = blockIdx.x;
    int flat = (bid & 7) * 196 + (bid >> 3);   // XCD swizzle, 1568 = 8*196 bijective
    const int mt = flat >> 1;                   // adjacent pair shares A-panel
    const int n0 = (flat & 1) << 7;
    const int m0 = mt << 7;

    // ---- staging source offsets: 4 gl2lds/thread/tile ----
    const int lc = (tid & 7) ^ ((tid >> 3) & 7);
    uint32_t abase[2], bbase[2];
    #pragma unroll
    for (int p = 0; p < 2; ++p) {
        int r  = (((tid >> 3) + 32 * p) << 1) + (lc >> 2);
        int m  = m0 + r;
        int n  = m / IMGHW;
        int rem = m - n * IMGHW;
        int h  = rem / HW_;
        int w  = rem - h * HW_;
        abase[p] = (uint32_t)((((n * HP + h) * HP + w) << 8) + ((lc & 3) << 4));
        bbase[p] = (uint32_t)((n0 + r) * (KSZ * 2) + ((lc & 3) << 4));
    }

    // ---- fragment LDS offsets ----
    const int fr = lane & 15, fg = lane >> 4;
    const int cp = (((fr & 1) << 2) | fg) ^ ((fr >> 1) & 7);
    const int wm0 = (wid >> 1) << 6;            // 0 / 64
    const int wn0 = (wid & 1) << 6;             // 0 / 64
    const int aB = (((wm0 >> 1) + (fr >> 1)) << 7) + (cp << 4);          // + mf*1024
    const int bB = 8192 + (((wn0 >> 1) + (fr >> 1)) << 7) + (cp << 4);   // + nf*1024

    const char* xtc = (const char*)xt;
    const char* wpc = (const char*)wpk;

    f32x4 acc[4][4];
    #pragma unroll
    for (int i = 0; i < 4; ++i)
        #pragma unroll
        for (int j = 0; j < 4; ++j)
            acc[i][j] = (f32x4){0.f, 0.f, 0.f, 0.f};

    auto STAGE = [&](int t, int buf) {          // K-tile t (BK=32)
        int tap = t >> 2;                       // 128/32 = 4 tiles per tap
        int kh = (tap * 11) >> 5;               // tap/3 for tap<9
        int kw = tap - kh * 3;
        uint32_t asl = (uint32_t)(((kh * HP + kw) << 8) + ((t & 3) << 6));
        uint32_t bsl = (uint32_t)(t << 6);
        char* L = &lds[buf][0];
        gl2lds16(xtc + abase[0] + asl, L + tid * 16);
        gl2lds16(xtc + abase[1] + asl, L + 4096 + tid * 16);
        gl2lds16(wpc + bbase[0] + bsl, L + 8192 + tid * 16);
        gl2lds16(wpc + bbase[1] + bsl, L + 12288 + tid * 16);
    };

    STAGE(0, 0);
    __syncthreads();

    #pragma unroll 1
    for (int t = 0; t < 36; ++t) {
        if (t < 35) STAGE(t + 1, (t + 1) & 1);
        const char* L = &lds[t & 1][0];
        ushort8 a[4], b[4];
        #pragma unroll
        for (int nf = 0; nf < 4; ++nf)
            b[nf] = *(const ushort8*)(L + bB + nf * 1024);
        #pragma unroll
        for (int mf = 0; mf < 4; ++mf)
            a[mf] = *(const ushort8*)(L + aB + mf * 1024);
        #pragma unroll
        for (int mf = 0; mf < 4; ++mf)
            #pragma unroll
            for (int nf = 0; nf < 4; ++nf)
                acc[mf][nf] = __builtin_amdgcn_mfma_f32_16x16x32_bf16(
                    __builtin_bit_cast(bf16x8, b[nf]),
                    __builtin_bit_cast(bf16x8, a[mf]),
                    acc[mf][nf], 0, 0, 0);
        __syncthreads();
    }

    // ---- epilogue: direct stores; D row=co, col=m; lanes 0-15 contiguous in w
    const int mwave = m0 + wm0;
    const int co0 = n0 + wn0 + (fg << 2);
    #pragma unroll
    for (int mf = 0; mf < 4; ++mf) {
        int m = mwave + mf * 16 + fr;
        int n = m / IMGHW;
        int hwr = m - n * IMGHW;
        uint32_t basem = (uint32_t)(n * (CO_ * IMGHW) + hwr);
        #pragma unroll
        for (int nf = 0; nf < 4; ++nf)
            #pragma unroll
            for (int q = 0; q < 4; ++q)
                out[basem + (uint32_t)(co0 + nf * 16 + q) * IMGHW] = acc[mf][nf][q];
    }
}

// ================= fallback (round-1 kernel, used if ws too small) ==========
#define BM    64
#define BK    32
#define NSTEP 36
#define LDSP  40

template<bool PACKED>
__global__ __launch_bounds__(256, 2)
void conv_fb(const float* __restrict__ x,
             const float* __restrict__ wraw,
             const unsigned short* __restrict__ wp,
             float* __restrict__ out)
{
    __shared__ __align__(16) unsigned short Al[2][BM][LDSP];
    __shared__ __align__(16) unsigned short Bl[2][CO_][LDSP];

    const int tid  = threadIdx.x;
    const int lane = tid & 63;
    const int wid  = tid >> 6;

    const int mb    = blockIdx.x;
    const int n_img = mb / 49;
    const int hw0   = (mb - n_img * 49) * BM;

    const int mm = lane;
    const int hw = hw0 + mm;
    const int h  = hw / HW_;
    const int w_ = hw - h * HW_;

    const int bco  = tid >> 2;
    const int bkkg = tid & 3;

    float   aPF[8];
    ushort8 bPF[4];

    auto loadA = [&](int step) {
        int khkw = step >> 2;
        int kh = khkw / 3, kw = khkw - (khkw / 3) * 3;
        int ci0 = (step & 3) * BK + wid * 8;
        int ih = h + kh - 1, iw = w_ + kw - 1;
        bool valid = ((unsigned)ih < (unsigned)HW_) && ((unsigned)iw < (unsigned)HW_);
        const float* px = x + (((size_t)(n_img * CIN + ci0) * HW_ + ih) * HW_ + iw);
        #pragma unroll
        for (int e = 0; e < 8; ++e)
            aPF[e] = valid ? px[e * IMGHW] : 0.f;
    };
    auto writeA = [&](int buf) {
        ushort8 v;
        #pragma unroll
        for (int e = 0; e < 8; ++e) v[e] = f2bf(aPF[e]);
        *(ushort8*)&Al[buf][mm][wid * 8] = v;
    };
    auto loadB = [&](int step) {
        if (PACKED) {
            int k0 = step * BK;
            #pragma unroll
            for (int r = 0; r < 4; ++r)
                bPF[r] = *(const ushort8*)&wp[(r * 64 + bco) * KSZ + k0 + bkkg * 8];
        } else {
            int khkw = step >> 2;
            int ci0 = (step & 3) * BK + bkkg * 8;
            #pragma unroll
            for (int r = 0; r < 4; ++r) {
                int co = r * 64 + bco;
                ushort8 v;
                #pragma unroll
                for (int e = 0; e < 8; ++e)
                    v[e] = f2bf(wraw[(co * CIN + ci0 + e) * 9 + khkw]);
                bPF[r] = v;
            }
        }
    };
    auto writeB = [&](int buf) {
        #pragma unroll
        for (int r = 0; r < 4; ++r)
            *(ushort8*)&Bl[buf][r * 64 + bco][bkkg * 8] = bPF[r];
    };

    f32x4 acc[4][4];
    #pragma unroll
    for (int i = 0; i < 4; ++i)
        #pragma unroll
        for (int j = 0; j < 4; ++j)
            acc[i][j] = (f32x4){0.f, 0.f, 0.f, 0.f};

    const int frow = lane & 15;
    const int fk   = (lane >> 4) * 8;

    loadA(0); loadB(0);
    writeA(0); writeB(0);
    __syncthreads();

    for (int s = 0; s < NSTEP; ++s) {
        const int cur = s & 1;
        if (s + 1 < NSTEP) { loadA(s + 1); loadB(s + 1); }

        ushort8 aF[4], bF[4];
        #pragma unroll
        for (int i = 0; i < 4; ++i)
            aF[i] = *(const ushort8*)&Bl[cur][wid * 64 + i * 16 + frow][fk];
        #pragma unroll
        for (int j = 0; j < 4; ++j)
            bF[j] = *(const ushort8*)&Al[cur][j * 16 + frow][fk];

        #pragma unroll
        for (int i = 0; i < 4; ++i)
            #pragma unroll
            for (int j = 0; j < 4; ++j)
                acc[i][j] = __builtin_amdgcn_mfma_f32_16x16x32_bf16(
                    __builtin_bit_cast(bf16x8, aF[i]),
                    __builtin_bit_cast(bf16x8, bF[j]),
                    acc[i][j], 0, 0, 0);

        if (s + 1 < NSTEP) { writeA(cur ^ 1); writeB(cur ^ 1); }
        __syncthreads();
    }

    float* ob = out + (size_t)n_img * (CO_ * IMGHW) + hw0;
    #pragma unroll
    for (int i = 0; i < 4; ++i) {
        int co0 = wid * 64 + i * 16 + (lane >> 4) * 4;
        #pragma unroll
        for (int j = 0; j < 4; ++j) {
            int mcol = j * 16 + (lane & 15);
            #pragma unroll
            for (int q = 0; q < 4; ++q)
                ob[(size_t)(co0 + q) * IMGHW + mcol] = acc[i][j][q];
        }
    }
}

extern "C" void kernel_launch(void* const* d_in, const int* in_sizes, int n_in,
                              void* d_out, int out_size, void* d_ws, size_t ws_size,
                              hipStream_t stream) {
    (void)in_sizes; (void)n_in; (void)out_size;
    const float* x  = (const float*)d_in[0];
    const float* wt = (const float*)d_in[1];
    float* out = (float*)d_out;

    if (ws_size >= WS_NEED) {
        unsigned short* xt  = (unsigned short*)d_ws;
        unsigned short* wpk = (unsigned short*)((char*)d_ws + XT_BYTES);
        xform<<<32 * HP, 256, 0, stream>>>(x, xt);
        pack_weight<<<(CO_ * KSZ) / 256, 256, 0, stream>>>(wt, wpk);
        conv97<<<1568, 256, 0, stream>>>(xt, wpk, out);
    } else if (ws_size >= WP_BYTES) {
        unsigned short* wpk = (unsigned short*)d_ws;
        pack_weight<<<(CO_ * KSZ) / 256, 256, 0, stream>>>(wt, wpk);
        conv_fb<true><<<100352 / BM, 256, 0, stream>>>(x, wt, wpk, out);
    } else {
        conv_fb<false><<<100352 / BM, 256, 0, stream>>>(x, wt, nullptr, out);
    }
}